// Round 16
// baseline (200.920 us; speedup 1.0000x reference)
//
#include <hip/hip_runtime.h>
#include <hip/hip_bf16.h>

#define L_SEQ 2048
#define DM 1024
#define DI 2048
#define DS 128
#define NH 32
#define HD 64
#define DPROJ 4384
#define DPAD 4480
#define NBATCH 2
#define NCH 8
#define CH 256
#define B_OFF 4096
#define C_OFF 4224
#define DT_OFF 4352
#define SWZ(row) ((((row) ^ ((row) >> 3)) & 7) << 4)

typedef unsigned short u16;
typedef __attribute__((ext_vector_type(8))) short short8;
typedef __attribute__((ext_vector_type(4))) float f32x4;

#define GLL16(g, l)                                                     \
  __builtin_amdgcn_global_load_lds(                                     \
      (const __attribute__((address_space(1))) unsigned int*)(g),       \
      (__attribute__((address_space(3))) unsigned int*)(l), 16, 0, 0)
#define SBAR __builtin_amdgcn_s_barrier()
#define MEMFENCE asm volatile("" ::: "memory")

__device__ __forceinline__ u16 f2bf(float f) {
  union { float f; unsigned u; } c; c.f = f;
  unsigned u = c.u;
  u += 0x7fffu + ((u >> 16) & 1u);
  return (u16)(u >> 16);
}
__device__ __forceinline__ float bf2f(u16 u) {
  return __uint_as_float((unsigned)u << 16);
}
__device__ __forceinline__ float siluf(float x) {
  return x / (1.0f + expf(-x));
}
__device__ __forceinline__ void store_out(u16* C, size_t o, float v) { C[o] = f2bf(v); }
__device__ __forceinline__ void store_out(float* C, size_t o, float v) { C[o] = v; }

// ------- prep: rmsnorm (blocks [0,M)) | cvt_w1 [M,M+DPAD) | cvt_w2 rest ----
__global__ __launch_bounds__(256) void prep_kernel(
    const float* __restrict__ x, const float* __restrict__ norm_w,
    const float* __restrict__ w1, const float* __restrict__ w2,
    u16* __restrict__ xnb, u16* __restrict__ w1b, u16* __restrict__ w2b,
    int M) {
  int bidx = blockIdx.x;
  int t = threadIdx.x;
  if (bidx < M) {
    const float* row = x + (size_t)bidx * DM;
    float4 v = *(const float4*)(row + t * 4);
    float ss = v.x * v.x + v.y * v.y + v.z * v.z + v.w * v.w;
#pragma unroll
    for (int o = 32; o > 0; o >>= 1) ss += __shfl_xor(ss, o);
    __shared__ float sred[4];
    if ((t & 63) == 0) sred[t >> 6] = ss;
    __syncthreads();
    ss = sred[0] + sred[1] + sred[2] + sred[3];
    float rs = rsqrtf(ss * (1.0f / DM) + 1e-6f);
    float4 wv = *(const float4*)(norm_w + t * 4);
    ushort4 o;
    o.x = f2bf(v.x * rs * wv.x);
    o.y = f2bf(v.y * rs * wv.y);
    o.z = f2bf(v.z * rs * wv.z);
    o.w = f2bf(v.w * rs * wv.w);
    *(ushort4*)(xnb + (size_t)bidx * DM + t * 4) = o;
  } else if (bidx < M + DPAD) {
    int r = bidx - M;
    int c = t * 4;
    ushort4 u;
    if (r < DPROJ) {
      float4 v = *(const float4*)(w1 + (size_t)r * DM + c);
      u.x = f2bf(v.x); u.y = f2bf(v.y); u.z = f2bf(v.z); u.w = f2bf(v.w);
    } else {
      u.x = 0; u.y = 0; u.z = 0; u.w = 0;
    }
    *(ushort4*)(w1b + (size_t)r * DM + c) = u;
  } else {
    size_t i = ((size_t)(bidx - M - DPAD) * 256 + t) * 8;
    float4 v0 = *(const float4*)(w2 + i);
    float4 v1 = *(const float4*)(w2 + i + 4);
    ushort4 a, b;
    a.x = f2bf(v0.x); a.y = f2bf(v0.y); a.z = f2bf(v0.z); a.w = f2bf(v0.w);
    b.x = f2bf(v1.x); b.y = f2bf(v1.y); b.z = f2bf(v1.z); b.w = f2bf(v1.w);
    *(ushort4*)(w2b + i) = a;
    *(ushort4*)(w2b + i + 4) = b;
  }
}

// ---------------- bf16 MFMA GEMM: C[m,n] = sum_k A[m,k]*B[n,k] ----------
// Triple-buffered LDS, counted vmcnt (never 0 in main loop), 1 barrier/K-step.
// SPLIT=2: grid doubles; swz&1 selects K-half; C has 2 planes of M*N.
template <typename OT, bool RES, bool DTS, int BN, int SPLIT>
__global__ __launch_bounds__(256, 4) void gemm_bt(
    const u16* __restrict__ A, const u16* __restrict__ Bw,
    OT* __restrict__ C, const float* __restrict__ resid,
    float* __restrict__ dts, int M, int N, int Kloop, int LDA, int nbx) {
  constexpr int WN = BN / 2;
  constexpr int NJ = WN / 16;
  __shared__ u16 lA[3][128 * 32];
  __shared__ u16 lB[3][BN * 32];
  const int tid = threadIdx.x;
  const int wv = tid >> 6, lane = tid & 63;
  const int wm = wv >> 1, wn = wv & 1;

  const int nwg = gridDim.x;
  const int cpx = nwg >> 3;
  const int wg = blockIdx.x;
  const int swz = (wg & 7) * cpx + (wg >> 3);
  int kh = 0, tile = swz;
  if (SPLIT == 2) { kh = swz & 1; tile = swz >> 1; }
  const int m0 = (tile / nbx) * 128, n0 = (tile % nbx) * BN;

  const u16* Ab = A + (size_t)kh * Kloop;
  const u16* Bb = Bw + (size_t)kh * Kloop;
  OT* Cb = (SPLIT == 2) ? (C + (size_t)kh * M * N) : C;

  const int rowS = tid >> 2;
  const int colS = (tid & 3) * 8;
  const u16* gA0 = Ab + (size_t)(m0 + rowS) * LDA + colS;
  const u16* gA1 = Ab + (size_t)(m0 + rowS + 64) * LDA + colS;
  const u16* gB0 = Bb + (size_t)(n0 + rowS) * LDA + colS;
  const u16* gB1 = Bb + (size_t)(n0 + rowS + 64) * LDA + colS;

  auto stage = [&](int kt, int buf) {
    const int ko = kt << 5;
    GLL16(gA0 + ko, &lA[buf][wv * 512]);
    GLL16(gA1 + ko, &lA[buf][2048 + wv * 512]);
    GLL16(gB0 + ko, &lB[buf][wv * 512]);
    if (BN == 128) GLL16(gB1 + ko, &lB[buf][2048 + wv * 512]);
  };

  f32x4 acc[4][NJ] = {};
  const int r = lane & 15;
  const int koff = (lane >> 4) * 8;

  auto compute = [&](int buf) {
    short8 af[4], bfr[NJ];
#pragma unroll
    for (int i = 0; i < 4; ++i)
      af[i] = *(const short8*)&lA[buf][(wm * 64 + i * 16 + r) * 32 + koff];
#pragma unroll
    for (int j = 0; j < NJ; ++j)
      bfr[j] = *(const short8*)&lB[buf][(wn * WN + j * 16 + r) * 32 + koff];
#pragma unroll
    for (int i = 0; i < 4; ++i)
#pragma unroll
      for (int j = 0; j < NJ; ++j)
        acc[i][j] = __builtin_amdgcn_mfma_f32_16x16x32_bf16(
            af[i], bfr[j], acc[i][j], 0, 0, 0);
  };

  const int nk = Kloop >> 5;
  stage(0, 0);
  stage(1, 1);
  int cur = 0;
  for (int kt = 0; kt < nk; ++kt) {
    if (kt + 1 < nk) {
      if (BN == 128) asm volatile("s_waitcnt vmcnt(4)" ::: "memory");
      else           asm volatile("s_waitcnt vmcnt(3)" ::: "memory");
    } else {
      asm volatile("s_waitcnt vmcnt(0)" ::: "memory");
    }
    SBAR;
    MEMFENCE;
    if (kt + 2 < nk) {
      int nb = cur + 2; if (nb >= 3) nb -= 3;
      stage(kt + 2, nb);
    }
    compute(cur);
    ++cur; if (cur == 3) cur = 0;
  }

  const int rbase = m0 + wm * 64 + (lane >> 4) * 4;
  const int cbase = n0 + wn * WN + (lane & 15);
#pragma unroll
  for (int i = 0; i < 4; ++i) {
#pragma unroll
    for (int j = 0; j < NJ; ++j) {
      int row0 = rbase + i * 16;
      int col = cbase + j * 16;
#pragma unroll
      for (int rr = 0; rr < 4; ++rr) {
        size_t o = (size_t)(row0 + rr) * N + col;
        float v = acc[i][j][rr];
        if (RES) v += resid[o];
        store_out(Cb, o, v);
        if (DTS) {
          if (col >= DT_OFF && col < DT_OFF + NH)
            dts[(size_t)(row0 + rr) * NH + (col - DT_OFF)] = v;
        }
      }
    }
  }
}

// ---------------- add_out: out = x + p0 + p1 ----------------
__global__ __launch_bounds__(256) void add_out_kernel(
    const float* __restrict__ x, const float* __restrict__ p,
    float* __restrict__ out) {
  size_t i = ((size_t)blockIdx.x * 256 + threadIdx.x) * 8;
  const float* p1 = p + (size_t)4096 * 1024;
#pragma unroll
  for (int q = 0; q < 2; ++q) {
    float4 a = *(const float4*)(x + i + q * 4);
    float4 b = *(const float4*)(p + i + q * 4);
    float4 c = *(const float4*)(p1 + i + q * 4);
    float4 o;
    o.x = a.x + b.x + c.x; o.y = a.y + b.y + c.y;
    o.z = a.z + b.z + c.z; o.w = a.w + b.w + c.w;
    *(float4*)(out + i + q * 4) = o;
  }
}

// ================= MFMA chunked scan =================
// Pass A (fused): conv(x)+SiLU inline (writes xhy for pass B), dt/a inline
// (writes dAdt); emits chunk-end state + chunk decay product.
__global__ __launch_bounds__(512) void scan_state_mfma(
    const u16* __restrict__ proj, const float* __restrict__ dts,
    const float* __restrict__ dt_bias, const float* __restrict__ A_log,
    const float* __restrict__ cw, const float* __restrict__ cb,
    u16* __restrict__ xhy, float* __restrict__ dAdt,
    float* __restrict__ S, float* __restrict__ P) {
  __shared__ u16 sBT[128 * 64];
  __shared__ u16 sXT[64 * 64];
  __shared__ u16 sXW[64 * 64];
  __shared__ float sDt[64], sCum[64], sWs[64], sLam[64];

  const int bid = blockIdx.x;
  const int ch = bid & 7, hh = (bid >> 3) & 31, b = bid >> 8;
  const int tid = threadIdx.x;
  const int w = tid >> 6, l = tid & 63;
  const int tw = w >> 1, half = w & 1;
  const int klane = (l >> 4) * 16;
  const size_t mchunk = (size_t)(b * L_SEQ + ch * CH);

  const int cvp0 = (tid & 7) * 8;
  float4 cwv[8];
  float cbv[8];
#pragma unroll
  for (int j = 0; j < 8; ++j) {
    cwv[j] = *(const float4*)(cw + (size_t)(hh * 64 + cvp0 + j) * 4);
    cbv[j] = cb[hh * 64 + cvp0 + j];
  }
  const float dtb_h = dt_bias[hh];
  const float eAh = expf(A_log[hh]);

  f32x4 hAcc[4] = {};
  float ctot = 0.0f;

  auto STAGE = [&](int sc) {
    const size_t m0 = mchunk + (size_t)sc * 64;
    {  // B rows -> sBT (transposed, row-pair packed)
      const int tp = tid >> 4;
      const int n0 = (tid & 15) * 8;
      const u16* r0 = proj + (m0 + 2 * tp) * DPAD + B_OFF + n0;
      short8 lo8 = *(const short8*)r0;
      short8 hi8 = *(const short8*)(r0 + DPAD);
#pragma unroll
      for (int q = 0; q < 8; ++q) {
        int n = n0 + q;
        unsigned v = (unsigned)(u16)lo8[q] | ((unsigned)(u16)hi8[q] << 16);
        *(unsigned*)((char*)sBT + ((n * 128 + 4 * tp) ^ SWZ(n))) = v;
      }
    }
    if (tid < 256) {  // conv(x)+silu for 2 steps -> sXT pair-packed + xhy
      const int q2 = tid >> 3;             // 0..31 -> steps 2q2, 2q2+1
      u16 bv[2][8];
#pragma unroll
      for (int s = 0; s < 2; ++s) {
        const int gm = (int)m0 + 2 * q2 + s;
        const int lrow = gm & (L_SEQ - 1);
        float accv[8];
#pragma unroll
        for (int j = 0; j < 8; ++j) accv[j] = cbv[j];
#pragma unroll
        for (int k = 0; k < 4; ++k) {
          if (lrow + k >= 3) {
            short8 rv = *(const short8*)(proj + (size_t)(gm + k - 3) * DPAD + DI +
                                         hh * 64 + cvp0);
#pragma unroll
            for (int j = 0; j < 8; ++j) {
              float wk = (k == 0) ? cwv[j].x : (k == 1) ? cwv[j].y
                        : (k == 2) ? cwv[j].z : cwv[j].w;
              accv[j] = fmaf(bf2f((u16)rv[j]), wk, accv[j]);
            }
          }
        }
        short8 o;
#pragma unroll
        for (int i = 0; i < 8; ++i) {
          bv[s][i] = f2bf(siluf(accv[i]));
          o[i] = (short)bv[s][i];
        }
        *(short8*)(xhy + (size_t)gm * DI + hh * 64 + cvp0) = o;
      }
#pragma unroll
      for (int i = 0; i < 8; ++i) {
        int p = cvp0 + i;
        unsigned pair = (unsigned)bv[0][i] | ((unsigned)bv[1][i] << 16);
        *(unsigned*)((char*)sXT + ((p * 128 + 4 * q2) ^ SWZ(p))) = pair;
      }
    }
    if (tid < 64) {  // dt/a inline + cumsum
      float raw = dts[(m0 + tid) * NH + hh] + dtb_h;
      float dtv = fmaxf(raw, 0.0f) + log1pf(expf(-fabsf(raw)));
      float a = -eAh * dtv;
      float2 ad; ad.x = a; ad.y = dtv;
      *(float2*)(dAdt + (m0 + tid) * 64 + hh * 2) = ad;
      sDt[tid] = dtv;
      float val = a;
#pragma unroll
      for (int o = 1; o < 64; o <<= 1) {
        float t2 = __shfl_up(val, o);
        if (tid >= o) val += t2;
      }
      sCum[tid] = val;
      float c63 = __shfl(val, 63);
      sWs[tid] = __expf(c63 - val) * dtv;
      sLam[tid] = __expf(val);
    }
  };

  STAGE(0);
  __syncthreads();

  for (int sc = 0; sc < 4; ++sc) {
    {
      int p = tid >> 3, sg = tid & 7;
      int byteX = (p * 128 + sg * 16) ^ SWZ(p);
      short8 xv = *(short8*)((char*)sXT + byteX);
      short8 outp;
#pragma unroll
      for (int j = 0; j < 8; ++j)
        outp[j] = (short)f2bf(bf2f((u16)xv[j]) * sWs[sg * 8 + j]);
      *(short8*)((char*)sXW + byteX) = outp;
    }
    __syncthreads();

    {
      float lam63 = sLam[63];
      ctot += sCum[63];
#pragma unroll
      for (int j = 0; j < 4; ++j) {
        hAcc[j][0] *= lam63; hAcc[j][1] *= lam63;
        hAcc[j][2] *= lam63; hAcc[j][3] *= lam63;
      }
      int prow = tw * 16 + (l & 15);
      short8 aXW[2];
#pragma unroll
      for (int kk = 0; kk < 2; ++kk)
        aXW[kk] = *(short8*)((char*)sXW + ((prow * 128 + kk * 64 + klane) ^ SWZ(prow)));
#pragma unroll
      for (int j = 0; j < 4; ++j) {
        int nrow = (half * 4 + j) * 16 + (l & 15);
#pragma unroll
        for (int kk = 0; kk < 2; ++kk) {
          short8 bBT = *(short8*)((char*)sBT + ((nrow * 128 + kk * 64 + klane) ^ SWZ(nrow)));
          hAcc[j] = __builtin_amdgcn_mfma_f32_16x16x32_bf16(aXW[kk], bBT, hAcc[j], 0, 0, 0);
        }
      }
    }
    __syncthreads();
    if (sc < 3) STAGE(sc + 1);
    __syncthreads();
  }

  float* Sb = S + (size_t)((b * 32 + hh) * NCH + ch) * 8192;
  const int p0 = tw * 16 + (l >> 4) * 4;
#pragma unroll
  for (int j = 0; j < 4; ++j) {
    int n = (half * 4 + j) * 16 + (l & 15);
#pragma unroll
    for (int r = 0; r < 4; ++r)
      Sb[(p0 + r) * 128 + n] = hAcc[j][r];
  }
  if (tid == 0) P[(b * 32 + hh) * NCH + ch] = __expf(ctot);
}

// Pass 2: sequential combine; S[c] becomes H0[c].
__global__ __launch_bounds__(256) void combine_kernel(
    float* __restrict__ S, const float* __restrict__ P) {
  int tid = blockIdx.x * 256 + threadIdx.x;
  int bh = tid >> 13, pn = tid & 8191;
  size_t base = (size_t)bh * NCH * 8192 + pn;
  float E = 0.0f;
#pragma unroll
  for (int c = 0; c < NCH; ++c) {
    size_t o = base + (size_t)c * 8192;
    float Sc = S[o];
    S[o] = E;
    E = fmaf(P[bh * NCH + c], E, Sc);
  }
}

// Pass B: y from H0, fused gate -> yb (xhy read-only).
__global__ __launch_bounds__(512) void scan_y_mfma(
    const u16* __restrict__ proj, const float* __restrict__ dAdt,
    const u16* __restrict__ xhy, const float* __restrict__ Dv,
    const float* __restrict__ S, u16* __restrict__ yb) {
  __shared__ u16 sC[64 * 128];
  __shared__ u16 sB[64 * 128];
  __shared__ u16 sHb[64 * 128];
  __shared__ u16 sBT[128 * 64];
  __shared__ u16 sXT[64 * 64];
  __shared__ u16 sXW[64 * 64];
  __shared__ u16 sW[64 * 64];
  __shared__ float sDt[64], sCum[64], sWs[64], sLam[64];

  const int bid = blockIdx.x;
  const int ch = bid & 7, hh = (bid >> 3) & 31, b = bid >> 8;
  const int tid = threadIdx.x;
  const int w = tid >> 6, l = tid & 63;
  const int tw = w >> 1, half = w & 1;
  const int klane = (l >> 4) * 16;
  const float Dh = Dv[hh];
  const size_t mchunk = (size_t)(b * L_SEQ + ch * CH);

  f32x4 hAcc[4];
  {
    const float* Sb = S + (size_t)((b * 32 + hh) * NCH + ch) * 8192;
    const int p0 = tw * 16 + (l >> 4) * 4;
#pragma unroll
    for (int j = 0; j < 4; ++j) {
      int n = (half * 4 + j) * 16 + (l & 15);
#pragma unroll
      for (int r = 0; r < 4; ++r)
        hAcc[j][r] = Sb[(p0 + r) * 128 + n];
    }
    int p = tid >> 3, sg = tid & 7;
#pragma unroll
    for (int i = 0; i < 4; ++i) {
      float4 v = *(const float4*)(Sb + p * 128 + sg * 16 + 4 * i);
      ushort4 u;
      u.x = f2bf(v.x); u.y = f2bf(v.y); u.z = f2bf(v.z); u.w = f2bf(v.w);
      *(ushort4*)((char*)sHb + ((p * 256 + (sg * 16 + 4 * i) * 2) ^ SWZ(p))) = u;
    }
  }

  auto STAGE = [&](int sc) {
    const size_t m0 = mchunk + (size_t)sc * 64;
    {
      const int tp = tid >> 4;
      const int n0 = (tid & 15) * 8;
      const u16* r0 = proj + (m0 + 2 * tp) * DPAD;
      short8 b0 = *(const short8*)(r0 + B_OFF + n0);
      short8 b1 = *(const short8*)(r0 + DPAD + B_OFF + n0);
      short8 c0v = *(const short8*)(r0 + C_OFF + n0);
      short8 c1v = *(const short8*)(r0 + DPAD + C_OFF + n0);
      *(short8*)((char*)sB + ((2 * tp * 256 + n0 * 2) ^ SWZ(2 * tp))) = b0;
      *(short8*)((char*)sB + (((2 * tp + 1) * 256 + n0 * 2) ^ SWZ(2 * tp + 1))) = b1;
      *(short8*)((char*)sC + ((2 * tp * 256 + n0 * 2) ^ SWZ(2 * tp))) = c0v;
      *(short8*)((char*)sC + (((2 * tp + 1) * 256 + n0 * 2) ^ SWZ(2 * tp + 1))) = c1v;
#pragma unroll
      for (int q = 0; q < 8; ++q) {
        int n = n0 + q;
        unsigned v = (unsigned)(u16)b0[q] | ((unsigned)(u16)b1[q] << 16);
        *(unsigned*)((char*)sBT + ((n * 128 + 4 * tp) ^ SWZ(n))) = v;
      }
    }
    if (tid < 256) {  // x -> sXT pair-packed (2 steps per thread)
      const int q2 = tid >> 3;
      const int p0 = (tid & 7) * 8;
      const u16* xr = xhy + (m0 + 2 * q2) * DI + hh * 64 + p0;
      short8 a0 = *(const short8*)xr;
      short8 a1 = *(const short8*)(xr + DI);
#pragma unroll
      for (int i = 0; i < 8; ++i) {
        int p = p0 + i;
        unsigned pair = (unsigned)(u16)a0[i] | ((unsigned)(u16)a1[i] << 16);
        *(unsigned*)((char*)sXT + ((p * 128 + 4 * q2) ^ SWZ(p))) = pair;
      }
    }
    if (tid < 64) {
      float2 ad = *(const float2*)(dAdt + (m0 + tid) * 64 + hh * 2);
      float a = ad.x, dtv = ad.y;
      sDt[tid] = dtv;
      float val = a;
#pragma unroll
      for (int o = 1; o < 64; o <<= 1) {
        float t2 = __shfl_up(val, o);
        if (tid >= o) val += t2;
      }
      sCum[tid] = val;
      float c63 = __shfl(val, 63);
      sWs[tid] = __expf(c63 - val) * dtv;
      sLam[tid] = __expf(val);
    }
  };

  STAGE(0);
  __syncthreads();

  for (int sc = 0; sc < 4; ++sc) {
    const size_t m0 = mchunk + (size_t)sc * 64;
    {
      int p = tid >> 3, sg = tid & 7;
      int byteX = (p * 128 + sg * 16) ^ SWZ(p);
      short8 xv = *(short8*)((char*)sXT + byteX);
      short8 outp;
#pragma unroll
      for (int j = 0; j < 8; ++j)
        outp[j] = (short)f2bf(bf2f((u16)xv[j]) * sWs[sg * 8 + j]);
      *(short8*)((char*)sXW + byteX) = outp;
    }
    __syncthreads();

    const int trow = tw * 16 + (l & 15);
    short8 aC[4];
#pragma unroll
    for (int kk = 0; kk < 4; ++kk)
      aC[kk] = *(short8*)((char*)sC + ((trow * 256 + kk * 64 + klane) ^ SWZ(trow)));

    {
      f32x4 g[2] = {};
#pragma unroll
      for (int sv2 = 0; sv2 < 2; ++sv2) {
        int srow = (half * 2 + sv2) * 16 + (l & 15);
#pragma unroll
        for (int kk = 0; kk < 4; ++kk) {
          short8 bB = *(short8*)((char*)sB + ((srow * 256 + kk * 64 + klane) ^ SWZ(srow)));
          g[sv2] = __builtin_amdgcn_mfma_f32_16x16x32_bf16(aC[kk], bB, g[sv2], 0, 0, 0);
        }
      }
#pragma unroll
      for (int sv2 = 0; sv2 < 2; ++sv2) {
        int s = (half * 2 + sv2) * 16 + (l & 15);
        float dts_ = sDt[s], cums = sCum[s];
#pragma unroll
        for (int r = 0; r < 4; ++r) {
          int t = tw * 16 + (l >> 4) * 4 + r;
          float v = (t >= s) ? g[sv2][r] * __expf(sCum[t] - cums) * dts_ : 0.0f;
          *(u16*)((char*)sW + ((t * 128 + 2 * s) ^ SWZ(t))) = f2bf(v);
        }
      }
    }
    __syncthreads();

    f32x4 y1[2] = {}, y2[2] = {};
    float lamv[4], lam63 = sLam[63];
#pragma unroll
    for (int r = 0; r < 4; ++r) lamv[r] = sLam[tw * 16 + (l >> 4) * 4 + r];
    {
      short8 aW[2];
#pragma unroll
      for (int kk = 0; kk < 2; ++kk)
        aW[kk] = *(short8*)((char*)sW + ((trow * 128 + kk * 64 + klane) ^ SWZ(trow)));
#pragma unroll
      for (int pv2 = 0; pv2 < 2; ++pv2) {
        int prow = (half * 2 + pv2) * 16 + (l & 15);
#pragma unroll
        for (int kk = 0; kk < 2; ++kk) {
          short8 bX = *(short8*)((char*)sXT + ((prow * 128 + kk * 64 + klane) ^ SWZ(prow)));
          y1[pv2] = __builtin_amdgcn_mfma_f32_16x16x32_bf16(aW[kk], bX, y1[pv2], 0, 0, 0);
        }
#pragma unroll
        for (int kk = 0; kk < 4; ++kk) {
          short8 bH = *(short8*)((char*)sHb + ((prow * 256 + kk * 64 + klane) ^ SWZ(prow)));
          y2[pv2] = __builtin_amdgcn_mfma_f32_16x16x32_bf16(aC[kk], bH, y2[pv2], 0, 0, 0);
        }
      }
#pragma unroll
      for (int j = 0; j < 4; ++j) {
        hAcc[j][0] *= lam63; hAcc[j][1] *= lam63;
        hAcc[j][2] *= lam63; hAcc[j][3] *= lam63;
      }
      short8 aXW[2];
#pragma unroll
      for (int kk = 0; kk < 2; ++kk)
        aXW[kk] = *(short8*)((char*)sXW + ((trow * 128 + kk * 64 + klane) ^ SWZ(trow)));
#pragma unroll
      for (int j = 0; j < 4; ++j) {
        int nrow = (half * 4 + j) * 16 + (l & 15);
#pragma unroll
        for (int kk = 0; kk < 2; ++kk) {
          short8 bBT = *(short8*)((char*)sBT + ((nrow * 128 + kk * 64 + klane) ^ SWZ(nrow)));
          hAcc[j] = __builtin_amdgcn_mfma_f32_16x16x32_bf16(aXW[kk], bBT, hAcc[j], 0, 0, 0);
        }
      }
    }
    __syncthreads();

    {
#pragma unroll
      for (int j = 0; j < 4; ++j) {
        int n = (half * 4 + j) * 16 + (l & 15);
#pragma unroll
        for (int r = 0; r < 4; ++r) {
          int p = tw * 16 + (l >> 4) * 4 + r;
          *(u16*)((char*)sHb + ((p * 256 + 2 * n) ^ SWZ(p))) = f2bf(hAcc[j][r]);
        }
      }
#pragma unroll
      for (int pv2 = 0; pv2 < 2; ++pv2) {
        int p = (half * 2 + pv2) * 16 + (l & 15);
#pragma unroll
        for (int r = 0; r < 4; ++r) {
          int t = tw * 16 + (l >> 4) * 4 + r;
          int col = hh * 64 + p;
          size_t gy = (m0 + t) * DI + col;
          float xv = bf2f(xhy[gy]);
          float yv = y1[pv2][r] + lamv[r] * y2[pv2][r] + Dh * xv;
          float zv = bf2f(proj[(m0 + t) * DPAD + col]);
          yb[gy] = f2bf(yv * siluf(zv));
        }
      }
      if (sc < 3) STAGE(sc + 1);
    }
    __syncthreads();
  }
}

extern "C" void kernel_launch(void* const* d_in, const int* in_sizes, int n_in,
                              void* d_out, int out_size, void* d_ws, size_t ws_size,
                              hipStream_t stream) {
  const float* x      = (const float*)d_in[0];
  const float* norm_w = (const float*)d_in[1];
  const float* w1     = (const float*)d_in[2];
  const float* cw     = (const float*)d_in[3];
  const float* cb     = (const float*)d_in[4];
  const float* A_log  = (const float*)d_in[5];
  const float* Dv     = (const float*)d_in[6];
  const float* dt_b   = (const float*)d_in[7];
  const float* w2     = (const float*)d_in[8];
  float* out = (float*)d_out;

  char* ws = (char*)d_ws;
  u16*   xnb  = (u16*)(ws);                    // 8,388,608
  u16*   w1b  = (u16*)(ws + 8388608);          // 9,175,040
  u16*   w2b  = (u16*)(ws + 17563648);         // 4,194,304
  u16*   proj = (u16*)(ws + 21757952);         // 36,700,160
  float* dts  = (float*)(ws + 58458112);       // 524,288
  u16*   xhy  = (u16*)(ws + 58982400);         // 16,777,216
  float* dAdt = (float*)(ws + 75759616);       // 1,048,576
  u16*   yb   = (u16*)(ws + 76808192);         // 16,777,216
  float* S    = (float*)(ws + 93585408);       // 16,777,216 (split-K plane 0)
  float* part = (float*)(ws + 93585408);       // 2 planes x 16,777,216
  float* P    = (float*)(ws + 127139840);      // 4,096

  const int M = NBATCH * L_SEQ;

  prep_kernel<<<M + DPAD + 1024, 256, 0, stream>>>(
      x, norm_w, w1, w2, xnb, w1b, w2b, M);
  gemm_bt<u16, false, true, 128, 1><<<(DPAD / 128) * (M / 128), 256, 0, stream>>>(
      xnb, w1b, proj, nullptr, dts, M, DPAD, DM, DM, DPAD / 128);
  scan_state_mfma<<<512, 512, 0, stream>>>(
      proj, dts, dt_b, A_log, cw, cb, xhy, dAdt, S, P);
  combine_kernel<<<2048, 256, 0, stream>>>(S, P);
  scan_y_mfma<<<512, 512, 0, stream>>>(proj, dAdt, xhy, Dv, S, yb);
  gemm_bt<float, false, false, 64, 2><<<2 * (DM / 64) * (M / 128), 256, 0, stream>>>(
      yb, w2b, part, nullptr, nullptr, M, DM, DI / 2, DI, DM / 64);
  add_out_kernel<<<M * DM / 2048, 256, 0, stream>>>(x, part, out);
}

// Round 17
// 191.545 us; speedup vs baseline: 1.0489x; 1.0489x over previous
//
#include <hip/hip_runtime.h>
#include <hip/hip_bf16.h>

#define L_SEQ 2048
#define DM 1024
#define DI 2048
#define DS 128
#define NH 32
#define HD 64
#define DPROJ 4384
#define DPAD 4480
#define NBATCH 2
#define NCH 8
#define CH 256
#define B_OFF 4096
#define C_OFF 4224
#define DT_OFF 4352
#define SWZ(row) ((((row) ^ ((row) >> 3)) & 7) << 4)

typedef unsigned short u16;
typedef __attribute__((ext_vector_type(8))) short short8;
typedef __attribute__((ext_vector_type(4))) float f32x4;

#define GLL16(g, l)                                                     \
  __builtin_amdgcn_global_load_lds(                                     \
      (const __attribute__((address_space(1))) unsigned int*)(g),       \
      (__attribute__((address_space(3))) unsigned int*)(l), 16, 0, 0)
#define SBAR __builtin_amdgcn_s_barrier()
#define MEMFENCE asm volatile("" ::: "memory")

__device__ __forceinline__ u16 f2bf(float f) {
  union { float f; unsigned u; } c; c.f = f;
  unsigned u = c.u;
  u += 0x7fffu + ((u >> 16) & 1u);
  return (u16)(u >> 16);
}
__device__ __forceinline__ float bf2f(u16 u) {
  return __uint_as_float((unsigned)u << 16);
}
__device__ __forceinline__ float siluf(float x) {
  return x / (1.0f + expf(-x));
}
__device__ __forceinline__ void store_out(u16* C, size_t o, float v) { C[o] = f2bf(v); }
__device__ __forceinline__ void store_out(float* C, size_t o, float v) { C[o] = v; }

// ------- prep: rmsnorm (blocks [0,M)) | cvt_w1 [M,M+DPAD) | cvt_w2 rest ----
__global__ __launch_bounds__(256) void prep_kernel(
    const float* __restrict__ x, const float* __restrict__ norm_w,
    const float* __restrict__ w1, const float* __restrict__ w2,
    u16* __restrict__ xnb, u16* __restrict__ w1b, u16* __restrict__ w2b,
    int M) {
  int bidx = blockIdx.x;
  int t = threadIdx.x;
  if (bidx < M) {
    const float* row = x + (size_t)bidx * DM;
    float4 v = *(const float4*)(row + t * 4);
    float ss = v.x * v.x + v.y * v.y + v.z * v.z + v.w * v.w;
#pragma unroll
    for (int o = 32; o > 0; o >>= 1) ss += __shfl_xor(ss, o);
    __shared__ float sred[4];
    if ((t & 63) == 0) sred[t >> 6] = ss;
    __syncthreads();
    ss = sred[0] + sred[1] + sred[2] + sred[3];
    float rs = rsqrtf(ss * (1.0f / DM) + 1e-6f);
    float4 wv = *(const float4*)(norm_w + t * 4);
    ushort4 o;
    o.x = f2bf(v.x * rs * wv.x);
    o.y = f2bf(v.y * rs * wv.y);
    o.z = f2bf(v.z * rs * wv.z);
    o.w = f2bf(v.w * rs * wv.w);
    *(ushort4*)(xnb + (size_t)bidx * DM + t * 4) = o;
  } else if (bidx < M + DPAD) {
    int r = bidx - M;
    int c = t * 4;
    ushort4 u;
    if (r < DPROJ) {
      float4 v = *(const float4*)(w1 + (size_t)r * DM + c);
      u.x = f2bf(v.x); u.y = f2bf(v.y); u.z = f2bf(v.z); u.w = f2bf(v.w);
    } else {
      u.x = 0; u.y = 0; u.z = 0; u.w = 0;
    }
    *(ushort4*)(w1b + (size_t)r * DM + c) = u;
  } else {
    size_t i = ((size_t)(bidx - M - DPAD) * 256 + t) * 8;
    float4 v0 = *(const float4*)(w2 + i);
    float4 v1 = *(const float4*)(w2 + i + 4);
    ushort4 a, b;
    a.x = f2bf(v0.x); a.y = f2bf(v0.y); a.z = f2bf(v0.z); a.w = f2bf(v0.w);
    b.x = f2bf(v1.x); b.y = f2bf(v1.y); b.z = f2bf(v1.z); b.w = f2bf(v1.w);
    *(ushort4*)(w2b + i) = a;
    *(ushort4*)(w2b + i + 4) = b;
  }
}

// ---------------- bf16 MFMA GEMM: C[m,n] = sum_k A[m,k]*B[n,k] ----------
// Triple-buffered LDS, counted vmcnt (never 0 in main loop), 1 barrier/K-step.
// SPLIT=2: grid doubles; swz&1 selects K-half; C has 2 planes of M*N.
template <typename OT, bool RES, bool DTS, int BN, int SPLIT>
__global__ __launch_bounds__(256, 4) void gemm_bt(
    const u16* __restrict__ A, const u16* __restrict__ Bw,
    OT* __restrict__ C, const float* __restrict__ resid,
    float* __restrict__ dts, int M, int N, int Kloop, int LDA, int nbx) {
  constexpr int WN = BN / 2;
  constexpr int NJ = WN / 16;
  __shared__ u16 lA[3][128 * 32];
  __shared__ u16 lB[3][BN * 32];
  const int tid = threadIdx.x;
  const int wv = tid >> 6, lane = tid & 63;
  const int wm = wv >> 1, wn = wv & 1;

  const int nwg = gridDim.x;
  const int cpx = nwg >> 3;
  const int wg = blockIdx.x;
  const int swz = (wg & 7) * cpx + (wg >> 3);
  int kh = 0, tile = swz;
  if (SPLIT == 2) { kh = swz & 1; tile = swz >> 1; }
  const int m0 = (tile / nbx) * 128, n0 = (tile % nbx) * BN;

  const u16* Ab = A + (size_t)kh * Kloop;
  const u16* Bb = Bw + (size_t)kh * Kloop;
  OT* Cb = (SPLIT == 2) ? (C + (size_t)kh * M * N) : C;

  const int rowS = tid >> 2;
  const int colS = (tid & 3) * 8;
  const u16* gA0 = Ab + (size_t)(m0 + rowS) * LDA + colS;
  const u16* gA1 = Ab + (size_t)(m0 + rowS + 64) * LDA + colS;
  const u16* gB0 = Bb + (size_t)(n0 + rowS) * LDA + colS;
  const u16* gB1 = Bb + (size_t)(n0 + rowS + 64) * LDA + colS;

  auto stage = [&](int kt, int buf) {
    const int ko = kt << 5;
    GLL16(gA0 + ko, &lA[buf][wv * 512]);
    GLL16(gA1 + ko, &lA[buf][2048 + wv * 512]);
    GLL16(gB0 + ko, &lB[buf][wv * 512]);
    if (BN == 128) GLL16(gB1 + ko, &lB[buf][2048 + wv * 512]);
  };

  f32x4 acc[4][NJ] = {};
  const int r = lane & 15;
  const int koff = (lane >> 4) * 8;

  auto compute = [&](int buf) {
    short8 af[4], bfr[NJ];
#pragma unroll
    for (int i = 0; i < 4; ++i)
      af[i] = *(const short8*)&lA[buf][(wm * 64 + i * 16 + r) * 32 + koff];
#pragma unroll
    for (int j = 0; j < NJ; ++j)
      bfr[j] = *(const short8*)&lB[buf][(wn * WN + j * 16 + r) * 32 + koff];
#pragma unroll
    for (int i = 0; i < 4; ++i)
#pragma unroll
      for (int j = 0; j < NJ; ++j)
        acc[i][j] = __builtin_amdgcn_mfma_f32_16x16x32_bf16(
            af[i], bfr[j], acc[i][j], 0, 0, 0);
  };

  const int nk = Kloop >> 5;
  stage(0, 0);
  stage(1, 1);
  int cur = 0;
  for (int kt = 0; kt < nk; ++kt) {
    if (kt + 1 < nk) {
      if (BN == 128) asm volatile("s_waitcnt vmcnt(4)" ::: "memory");
      else           asm volatile("s_waitcnt vmcnt(3)" ::: "memory");
    } else {
      asm volatile("s_waitcnt vmcnt(0)" ::: "memory");
    }
    SBAR;
    MEMFENCE;
    if (kt + 2 < nk) {
      int nb = cur + 2; if (nb >= 3) nb -= 3;
      stage(kt + 2, nb);
    }
    compute(cur);
    ++cur; if (cur == 3) cur = 0;
  }

  const int rbase = m0 + wm * 64 + (lane >> 4) * 4;
  const int cbase = n0 + wn * WN + (lane & 15);
#pragma unroll
  for (int i = 0; i < 4; ++i) {
#pragma unroll
    for (int j = 0; j < NJ; ++j) {
      int row0 = rbase + i * 16;
      int col = cbase + j * 16;
#pragma unroll
      for (int rr = 0; rr < 4; ++rr) {
        size_t o = (size_t)(row0 + rr) * N + col;
        float v = acc[i][j][rr];
        if (RES) v += resid[o];
        store_out(Cb, o, v);
        if (DTS) {
          if (col >= DT_OFF && col < DT_OFF + NH)
            dts[(size_t)(row0 + rr) * NH + (col - DT_OFF)] = v;
        }
      }
    }
  }
}

// ---------------- add_out: out = x + p0 + p1 ----------------
__global__ __launch_bounds__(256) void add_out_kernel(
    const float* __restrict__ x, const float* __restrict__ p,
    float* __restrict__ out) {
  size_t i = ((size_t)blockIdx.x * 256 + threadIdx.x) * 8;
  const float* p1 = p + (size_t)4096 * 1024;
#pragma unroll
  for (int q = 0; q < 2; ++q) {
    float4 a = *(const float4*)(x + i + q * 4);
    float4 b = *(const float4*)(p + i + q * 4);
    float4 c = *(const float4*)(p1 + i + q * 4);
    float4 o;
    o.x = a.x + b.x + c.x; o.y = a.y + b.y + c.y;
    o.z = a.z + b.z + c.z; o.w = a.w + b.w + c.w;
    *(float4*)(out + i + q * 4) = o;
  }
}

// ================= MFMA chunked scan =================
// Pass A (fused): conv(x)+SiLU inline (writes xhy for pass B), dt/a inline
// (writes dAdt); emits chunk-end state + chunk decay product.
__global__ __launch_bounds__(512) void scan_state_mfma(
    const u16* __restrict__ proj, const float* __restrict__ dts,
    const float* __restrict__ dt_bias, const float* __restrict__ A_log,
    const float* __restrict__ cw, const float* __restrict__ cb,
    u16* __restrict__ xhy, float* __restrict__ dAdt,
    float* __restrict__ S, float* __restrict__ P) {
  __shared__ u16 sBT[128 * 64];
  __shared__ u16 sXT[64 * 64];
  __shared__ u16 sXW[64 * 64];
  __shared__ float sDt[64], sCum[64], sWs[64], sLam[64];

  const int bid = blockIdx.x;
  const int ch = bid & 7, hh = (bid >> 3) & 31, b = bid >> 8;
  const int tid = threadIdx.x;
  const int w = tid >> 6, l = tid & 63;
  const int tw = w >> 1, half = w & 1;
  const int klane = (l >> 4) * 16;
  const size_t mchunk = (size_t)(b * L_SEQ + ch * CH);

  const int cvp0 = (tid & 7) * 8;
  float4 cwv[8];
  float cbv[8];
#pragma unroll
  for (int j = 0; j < 8; ++j) {
    cwv[j] = *(const float4*)(cw + (size_t)(hh * 64 + cvp0 + j) * 4);
    cbv[j] = cb[hh * 64 + cvp0 + j];
  }
  const float dtb_h = dt_bias[hh];
  const float eAh = expf(A_log[hh]);

  f32x4 hAcc[4] = {};
  float ctot = 0.0f;

  auto STAGE = [&](int sc) {
    const size_t m0 = mchunk + (size_t)sc * 64;
    {  // B rows -> sBT (transposed, row-pair packed)
      const int tp = tid >> 4;
      const int n0 = (tid & 15) * 8;
      const u16* r0 = proj + (m0 + 2 * tp) * DPAD + B_OFF + n0;
      short8 lo8 = *(const short8*)r0;
      short8 hi8 = *(const short8*)(r0 + DPAD);
#pragma unroll
      for (int q = 0; q < 8; ++q) {
        int n = n0 + q;
        unsigned v = (unsigned)(u16)lo8[q] | ((unsigned)(u16)hi8[q] << 16);
        *(unsigned*)((char*)sBT + ((n * 128 + 4 * tp) ^ SWZ(n))) = v;
      }
    }
    {  // conv(x)+silu -> sXT (transposed) + xhy (for pass B)
      const int sx = tid >> 3;
      const int gm = (int)m0 + sx;
      const int lrow = gm & (L_SEQ - 1);
      float accv[8];
#pragma unroll
      for (int j = 0; j < 8; ++j) accv[j] = cbv[j];
#pragma unroll
      for (int k = 0; k < 4; ++k) {
        if (lrow + k >= 3) {
          short8 rv = *(const short8*)(proj + (size_t)(gm + k - 3) * DPAD + DI +
                                       hh * 64 + cvp0);
#pragma unroll
          for (int j = 0; j < 8; ++j) {
            float wk = (k == 0) ? cwv[j].x : (k == 1) ? cwv[j].y
                      : (k == 2) ? cwv[j].z : cwv[j].w;
            accv[j] = fmaf(bf2f((u16)rv[j]), wk, accv[j]);
          }
        }
      }
      short8 o;
#pragma unroll
      for (int i = 0; i < 8; ++i) {
        u16 bv = f2bf(siluf(accv[i]));
        o[i] = (short)bv;
        int p = cvp0 + i;
        *(u16*)((char*)sXT + ((p * 128 + 2 * sx) ^ SWZ(p))) = bv;
      }
      *(short8*)(xhy + (size_t)gm * DI + hh * 64 + cvp0) = o;
    }
    if (tid < 64) {  // dt/a inline + cumsum
      float raw = dts[(m0 + tid) * NH + hh] + dtb_h;
      float dtv = fmaxf(raw, 0.0f) + log1pf(expf(-fabsf(raw)));
      float a = -eAh * dtv;
      float2 ad; ad.x = a; ad.y = dtv;
      *(float2*)(dAdt + (m0 + tid) * 64 + hh * 2) = ad;
      sDt[tid] = dtv;
      float val = a;
#pragma unroll
      for (int o = 1; o < 64; o <<= 1) {
        float t2 = __shfl_up(val, o);
        if (tid >= o) val += t2;
      }
      sCum[tid] = val;
      float c63 = __shfl(val, 63);
      sWs[tid] = __expf(c63 - val) * dtv;
      sLam[tid] = __expf(val);
    }
  };

  STAGE(0);
  __syncthreads();

  for (int sc = 0; sc < 4; ++sc) {
    {
      int p = tid >> 3, sg = tid & 7;
      int byteX = (p * 128 + sg * 16) ^ SWZ(p);
      short8 xv = *(short8*)((char*)sXT + byteX);
      short8 outp;
#pragma unroll
      for (int j = 0; j < 8; ++j)
        outp[j] = (short)f2bf(bf2f((u16)xv[j]) * sWs[sg * 8 + j]);
      *(short8*)((char*)sXW + byteX) = outp;
    }
    __syncthreads();

    {
      float lam63 = sLam[63];
      ctot += sCum[63];
#pragma unroll
      for (int j = 0; j < 4; ++j) {
        hAcc[j][0] *= lam63; hAcc[j][1] *= lam63;
        hAcc[j][2] *= lam63; hAcc[j][3] *= lam63;
      }
      int prow = tw * 16 + (l & 15);
      short8 aXW[2];
#pragma unroll
      for (int kk = 0; kk < 2; ++kk)
        aXW[kk] = *(short8*)((char*)sXW + ((prow * 128 + kk * 64 + klane) ^ SWZ(prow)));
#pragma unroll
      for (int j = 0; j < 4; ++j) {
        int nrow = (half * 4 + j) * 16 + (l & 15);
#pragma unroll
        for (int kk = 0; kk < 2; ++kk) {
          short8 bBT = *(short8*)((char*)sBT + ((nrow * 128 + kk * 64 + klane) ^ SWZ(nrow)));
          hAcc[j] = __builtin_amdgcn_mfma_f32_16x16x32_bf16(aXW[kk], bBT, hAcc[j], 0, 0, 0);
        }
      }
    }
    __syncthreads();
    if (sc < 3) STAGE(sc + 1);
    __syncthreads();
  }

  float* Sb = S + (size_t)((b * 32 + hh) * NCH + ch) * 8192;
  const int p0 = tw * 16 + (l >> 4) * 4;
#pragma unroll
  for (int j = 0; j < 4; ++j) {
    int n = (half * 4 + j) * 16 + (l & 15);
#pragma unroll
    for (int r = 0; r < 4; ++r)
      Sb[(p0 + r) * 128 + n] = hAcc[j][r];
  }
  if (tid == 0) P[(b * 32 + hh) * NCH + ch] = __expf(ctot);
}

// Pass 2: sequential combine; S[c] becomes H0[c].
__global__ __launch_bounds__(256) void combine_kernel(
    float* __restrict__ S, const float* __restrict__ P) {
  int tid = blockIdx.x * 256 + threadIdx.x;
  int bh = tid >> 13, pn = tid & 8191;
  size_t base = (size_t)bh * NCH * 8192 + pn;
  float E = 0.0f;
#pragma unroll
  for (int c = 0; c < NCH; ++c) {
    size_t o = base + (size_t)c * 8192;
    float Sc = S[o];
    S[o] = E;
    E = fmaf(P[bh * NCH + c], E, Sc);
  }
}

// Pass B: y from H0, fused gate -> yb (xhy read-only).
__global__ __launch_bounds__(512) void scan_y_mfma(
    const u16* __restrict__ proj, const float* __restrict__ dAdt,
    const u16* __restrict__ xhy, const float* __restrict__ Dv,
    const float* __restrict__ S, u16* __restrict__ yb) {
  __shared__ u16 sC[64 * 128];
  __shared__ u16 sB[64 * 128];
  __shared__ u16 sHb[64 * 128];
  __shared__ u16 sBT[128 * 64];
  __shared__ u16 sXT[64 * 64];
  __shared__ u16 sXW[64 * 64];
  __shared__ u16 sW[64 * 64];
  __shared__ float sDt[64], sCum[64], sWs[64], sLam[64];

  const int bid = blockIdx.x;
  const int ch = bid & 7, hh = (bid >> 3) & 31, b = bid >> 8;
  const int tid = threadIdx.x;
  const int w = tid >> 6, l = tid & 63;
  const int tw = w >> 1, half = w & 1;
  const int klane = (l >> 4) * 16;
  const float Dh = Dv[hh];
  const size_t mchunk = (size_t)(b * L_SEQ + ch * CH);

  f32x4 hAcc[4];
  {
    const float* Sb = S + (size_t)((b * 32 + hh) * NCH + ch) * 8192;
    const int p0 = tw * 16 + (l >> 4) * 4;
#pragma unroll
    for (int j = 0; j < 4; ++j) {
      int n = (half * 4 + j) * 16 + (l & 15);
#pragma unroll
      for (int r = 0; r < 4; ++r)
        hAcc[j][r] = Sb[(p0 + r) * 128 + n];
    }
    int p = tid >> 3, sg = tid & 7;
#pragma unroll
    for (int i = 0; i < 4; ++i) {
      float4 v = *(const float4*)(Sb + p * 128 + sg * 16 + 4 * i);
      ushort4 u;
      u.x = f2bf(v.x); u.y = f2bf(v.y); u.z = f2bf(v.z); u.w = f2bf(v.w);
      *(ushort4*)((char*)sHb + ((p * 256 + (sg * 16 + 4 * i) * 2) ^ SWZ(p))) = u;
    }
  }

  auto STAGE = [&](int sc) {
    const size_t m0 = mchunk + (size_t)sc * 64;
    {
      const int tp = tid >> 4;
      const int n0 = (tid & 15) * 8;
      const u16* r0 = proj + (m0 + 2 * tp) * DPAD;
      short8 b0 = *(const short8*)(r0 + B_OFF + n0);
      short8 b1 = *(const short8*)(r0 + DPAD + B_OFF + n0);
      short8 c0v = *(const short8*)(r0 + C_OFF + n0);
      short8 c1v = *(const short8*)(r0 + DPAD + C_OFF + n0);
      *(short8*)((char*)sB + ((2 * tp * 256 + n0 * 2) ^ SWZ(2 * tp))) = b0;
      *(short8*)((char*)sB + (((2 * tp + 1) * 256 + n0 * 2) ^ SWZ(2 * tp + 1))) = b1;
      *(short8*)((char*)sC + ((2 * tp * 256 + n0 * 2) ^ SWZ(2 * tp))) = c0v;
      *(short8*)((char*)sC + (((2 * tp + 1) * 256 + n0 * 2) ^ SWZ(2 * tp + 1))) = c1v;
#pragma unroll
      for (int q = 0; q < 8; ++q) {
        int n = n0 + q;
        unsigned v = (unsigned)(u16)b0[q] | ((unsigned)(u16)b1[q] << 16);
        *(unsigned*)((char*)sBT + ((n * 128 + 4 * tp) ^ SWZ(n))) = v;
      }
    }
    {
      const int sx = tid >> 3;
      const int p0 = (tid & 7) * 8;
      short8 xv8 = *(const short8*)(xhy + (m0 + sx) * DI + hh * 64 + p0);
#pragma unroll
      for (int i = 0; i < 8; ++i) {
        int p = p0 + i;
        *(u16*)((char*)sXT + ((p * 128 + 2 * sx) ^ SWZ(p))) = (u16)xv8[i];
      }
    }
    if (tid < 64) {
      float2 ad = *(const float2*)(dAdt + (m0 + tid) * 64 + hh * 2);
      float a = ad.x, dtv = ad.y;
      sDt[tid] = dtv;
      float val = a;
#pragma unroll
      for (int o = 1; o < 64; o <<= 1) {
        float t2 = __shfl_up(val, o);
        if (tid >= o) val += t2;
      }
      sCum[tid] = val;
      float c63 = __shfl(val, 63);
      sWs[tid] = __expf(c63 - val) * dtv;
      sLam[tid] = __expf(val);
    }
  };

  STAGE(0);
  __syncthreads();

  for (int sc = 0; sc < 4; ++sc) {
    const size_t m0 = mchunk + (size_t)sc * 64;
    {
      int p = tid >> 3, sg = tid & 7;
      int byteX = (p * 128 + sg * 16) ^ SWZ(p);
      short8 xv = *(short8*)((char*)sXT + byteX);
      short8 outp;
#pragma unroll
      for (int j = 0; j < 8; ++j)
        outp[j] = (short)f2bf(bf2f((u16)xv[j]) * sWs[sg * 8 + j]);
      *(short8*)((char*)sXW + byteX) = outp;
    }
    __syncthreads();

    const int trow = tw * 16 + (l & 15);
    short8 aC[4];
#pragma unroll
    for (int kk = 0; kk < 4; ++kk)
      aC[kk] = *(short8*)((char*)sC + ((trow * 256 + kk * 64 + klane) ^ SWZ(trow)));

    {
      f32x4 g[2] = {};
#pragma unroll
      for (int sv2 = 0; sv2 < 2; ++sv2) {
        int srow = (half * 2 + sv2) * 16 + (l & 15);
#pragma unroll
        for (int kk = 0; kk < 4; ++kk) {
          short8 bB = *(short8*)((char*)sB + ((srow * 256 + kk * 64 + klane) ^ SWZ(srow)));
          g[sv2] = __builtin_amdgcn_mfma_f32_16x16x32_bf16(aC[kk], bB, g[sv2], 0, 0, 0);
        }
      }
#pragma unroll
      for (int sv2 = 0; sv2 < 2; ++sv2) {
        int s = (half * 2 + sv2) * 16 + (l & 15);
        float dts_ = sDt[s], cums = sCum[s];
#pragma unroll
        for (int r = 0; r < 4; ++r) {
          int t = tw * 16 + (l >> 4) * 4 + r;
          float v = (t >= s) ? g[sv2][r] * __expf(sCum[t] - cums) * dts_ : 0.0f;
          *(u16*)((char*)sW + ((t * 128 + 2 * s) ^ SWZ(t))) = f2bf(v);
        }
      }
    }
    __syncthreads();

    f32x4 y1[2] = {}, y2[2] = {};
    float lamv[4], lam63 = sLam[63];
#pragma unroll
    for (int r = 0; r < 4; ++r) lamv[r] = sLam[tw * 16 + (l >> 4) * 4 + r];
    {
      short8 aW[2];
#pragma unroll
      for (int kk = 0; kk < 2; ++kk)
        aW[kk] = *(short8*)((char*)sW + ((trow * 128 + kk * 64 + klane) ^ SWZ(trow)));
#pragma unroll
      for (int pv2 = 0; pv2 < 2; ++pv2) {
        int prow = (half * 2 + pv2) * 16 + (l & 15);
#pragma unroll
        for (int kk = 0; kk < 2; ++kk) {
          short8 bX = *(short8*)((char*)sXT + ((prow * 128 + kk * 64 + klane) ^ SWZ(prow)));
          y1[pv2] = __builtin_amdgcn_mfma_f32_16x16x32_bf16(aW[kk], bX, y1[pv2], 0, 0, 0);
        }
#pragma unroll
        for (int kk = 0; kk < 4; ++kk) {
          short8 bH = *(short8*)((char*)sHb + ((prow * 256 + kk * 64 + klane) ^ SWZ(prow)));
          y2[pv2] = __builtin_amdgcn_mfma_f32_16x16x32_bf16(aC[kk], bH, y2[pv2], 0, 0, 0);
        }
      }
#pragma unroll
      for (int j = 0; j < 4; ++j) {
        hAcc[j][0] *= lam63; hAcc[j][1] *= lam63;
        hAcc[j][2] *= lam63; hAcc[j][3] *= lam63;
      }
      short8 aXW[2];
#pragma unroll
      for (int kk = 0; kk < 2; ++kk)
        aXW[kk] = *(short8*)((char*)sXW + ((trow * 128 + kk * 64 + klane) ^ SWZ(trow)));
#pragma unroll
      for (int j = 0; j < 4; ++j) {
        int nrow = (half * 4 + j) * 16 + (l & 15);
#pragma unroll
        for (int kk = 0; kk < 2; ++kk) {
          short8 bBT = *(short8*)((char*)sBT + ((nrow * 128 + kk * 64 + klane) ^ SWZ(nrow)));
          hAcc[j] = __builtin_amdgcn_mfma_f32_16x16x32_bf16(aXW[kk], bBT, hAcc[j], 0, 0, 0);
        }
      }
    }
    __syncthreads();

    {
#pragma unroll
      for (int j = 0; j < 4; ++j) {
        int n = (half * 4 + j) * 16 + (l & 15);
#pragma unroll
        for (int r = 0; r < 4; ++r) {
          int p = tw * 16 + (l >> 4) * 4 + r;
          *(u16*)((char*)sHb + ((p * 256 + 2 * n) ^ SWZ(p))) = f2bf(hAcc[j][r]);
        }
      }
#pragma unroll
      for (int pv2 = 0; pv2 < 2; ++pv2) {
        int p = (half * 2 + pv2) * 16 + (l & 15);
#pragma unroll
        for (int r = 0; r < 4; ++r) {
          int t = tw * 16 + (l >> 4) * 4 + r;
          int col = hh * 64 + p;
          size_t gy = (m0 + t) * DI + col;
          float xv = bf2f(xhy[gy]);
          float yv = y1[pv2][r] + lamv[r] * y2[pv2][r] + Dh * xv;
          float zv = bf2f(proj[(m0 + t) * DPAD + col]);
          yb[gy] = f2bf(yv * siluf(zv));
        }
      }
      if (sc < 3) STAGE(sc + 1);
    }
    __syncthreads();
  }
}

extern "C" void kernel_launch(void* const* d_in, const int* in_sizes, int n_in,
                              void* d_out, int out_size, void* d_ws, size_t ws_size,
                              hipStream_t stream) {
  const float* x      = (const float*)d_in[0];
  const float* norm_w = (const float*)d_in[1];
  const float* w1     = (const float*)d_in[2];
  const float* cw     = (const float*)d_in[3];
  const float* cb     = (const float*)d_in[4];
  const float* A_log  = (const float*)d_in[5];
  const float* Dv     = (const float*)d_in[6];
  const float* dt_b   = (const float*)d_in[7];
  const float* w2     = (const float*)d_in[8];
  float* out = (float*)d_out;

  char* ws = (char*)d_ws;
  u16*   xnb  = (u16*)(ws);                    // 8,388,608
  u16*   w1b  = (u16*)(ws + 8388608);          // 9,175,040
  u16*   w2b  = (u16*)(ws + 17563648);         // 4,194,304
  u16*   proj = (u16*)(ws + 21757952);         // 36,700,160
  float* dts  = (float*)(ws + 58458112);       // 524,288
  u16*   xhy  = (u16*)(ws + 58982400);         // 16,777,216
  float* dAdt = (float*)(ws + 75759616);       // 1,048,576
  u16*   yb   = (u16*)(ws + 76808192);         // 16,777,216
  float* S    = (float*)(ws + 93585408);       // 16,777,216 (split-K plane 0)
  float* part = (float*)(ws + 93585408);       // 2 planes x 16,777,216
  float* P    = (float*)(ws + 127139840);      // 4,096

  const int M = NBATCH * L_SEQ;

  prep_kernel<<<M + DPAD + 1024, 256, 0, stream>>>(
      x, norm_w, w1, w2, xnb, w1b, w2b, M);
  gemm_bt<u16, false, true, 128, 1><<<(DPAD / 128) * (M / 128), 256, 0, stream>>>(
      xnb, w1b, proj, nullptr, dts, M, DPAD, DM, DM, DPAD / 128);
  scan_state_mfma<<<512, 512, 0, stream>>>(
      proj, dts, dt_b, A_log, cw, cb, xhy, dAdt, S, P);
  combine_kernel<<<2048, 256, 0, stream>>>(S, P);
  scan_y_mfma<<<512, 512, 0, stream>>>(proj, dAdt, xhy, Dv, S, yb);
  gemm_bt<float, false, false, 64, 2><<<2 * (DM / 64) * (M / 128), 256, 0, stream>>>(
      yb, w2b, part, nullptr, nullptr, M, DM, DI / 2, DI, DM / 64);
  add_out_kernel<<<M * DM / 2048, 256, 0, stream>>>(x, part, out);
}